// Round 11
// baseline (234.516 us; speedup 1.0000x reference)
//
#include <hip/hip_runtime.h>

#define DIM    512
#define BATCH  2048
#define NDRUG  2000
#define H1     128
#define H2     64
#define NITEM  65        // 1 pos + 64 neg per sample
#define SLAB   774144    // floats: P 2000x128 | Q 2000x128 | Qt 2048x128
#define W2F_OFF  (SLAB)               // 16 KB  W2 bf16 B-fragments
#define W1F_OFF  (W2F_OFF + 4096)     // 256 KB W1 bf16 B-fragments
#define LP       65                   // layer1 LDS pitch in short8 (+1 pad)
#define REP      8                    // attribution: x8 repeat, z=0 offsets

typedef __attribute__((ext_vector_type(8))) short short8;
typedef __attribute__((ext_vector_type(4))) float floatx4;

// f32 -> bf16 RNE (bit trick; inputs finite)
__device__ inline unsigned f2bf(float x) {
    union { float f; unsigned u; } v; v.f = x;
    unsigned r = v.u + 0x7fffu + ((v.u >> 16) & 1u);
    return r >> 16;
}
__device__ inline unsigned pkbf(float a, float b) {
    return f2bf(a) | (f2bf(b) << 16);
}
__device__ inline short8 cvt8(const float* __restrict__ src) {
    float4 a = *(const float4*)src, b = *(const float4*)(src + 4);
    union { short8 s; unsigned u[4]; } v;
    v.u[0] = pkbf(a.x, a.y); v.u[1] = pkbf(a.z, a.w);
    v.u[2] = pkbf(b.x, b.y); v.u[3] = pkbf(b.z, b.w);
    return v.s;
}

// ---------------------------------------------------------------------------
// Kernel 1: weight packing (x REP, z=0 so every rep is the identical work —
// runtime z defeats loop-invariant hoisting). 65 blocks x 256.
// W1f storage index = (half*8 + nt)*16 + kt ; W2f storage index = kt*4 + nt.
// ---------------------------------------------------------------------------
__global__ __launch_bounds__(256) void pack_w(
    const float* __restrict__ W1, const float* __restrict__ W2,
    float* __restrict__ ws, int z)
{
    const int blk = blockIdx.x, tid = threadIdx.x;
    #pragma unroll 1
    for (int rep = 0; rep < REP; ++rep) {
        const size_t zo = (size_t)(z * rep);
        const float* W1r = W1 + zo;
        const float* W2r = W2 + zo;
        if (blk < 64) {
            short8* W1f = (short8*)(ws + W1F_OFF + zo);
            int item = blk * 256 + tid;                // < 16384
            int frag = item >> 6, fl = item & 63;
            int half = frag >> 7, rem = frag & 127;
            int nt = rem >> 4, kt = rem & 15;
            int fn = fl & 15, fq = fl >> 4;
            short8 v;
            #pragma unroll
            for (int j = 0; j < 8; ++j) {
                int k = half * DIM + kt * 32 + fq * 8 + j;
                v[j] = (short)f2bf(W1r[k * H1 + nt * 16 + fn]);
            }
            W1f[item] = v;
        } else {
            short8* W2f = (short8*)(ws + W2F_OFF + zo);
            #pragma unroll
            for (int i = 0; i < 4; ++i) {
                int item = i * 256 + tid;              // < 1024
                int frag = item >> 6, fl = item & 63;
                int kt = frag >> 2, nt = frag & 3;
                int fn = fl & 15, fq = fl >> 4;
                short8 v;
                #pragma unroll
                for (int j = 0; j < 8; ++j)
                    v[j] = (short)f2bf(W2r[(kt * 32 + fq * 8 + j) * H2 + nt * 16 + fn]);
                W2f[item] = v;
            }
        }
    }
}

// ---------------------------------------------------------------------------
// layer-1 MFMA core (unchanged from R10): NT col-tiles, K=512, double-
// buffered bulk B-loads. Frag (i,kt) at Wh[(i*16 + kt)*64 + lane].
// ---------------------------------------------------------------------------
template<int NT>
__device__ inline void l1_core(const short8* __restrict__ Wh,
                               const short8* __restrict__ ldsA,
                               int n, int q, int lane, floatx4* acc)
{
    short8 B[2][NT * 4];
    #pragma unroll
    for (int i = 0; i < NT; ++i)
        #pragma unroll
        for (int k = 0; k < 4; ++k)
            B[0][i * 4 + k] = Wh[(i * 16 + k) * 64 + lane];

    #pragma unroll
    for (int g = 0; g < 4; ++g) {
        const int cur = g & 1, nxt = cur ^ 1;
        if (g < 3) {
            #pragma unroll
            for (int i = 0; i < NT; ++i)
                #pragma unroll
                for (int k = 0; k < 4; ++k)
                    B[nxt][i * 4 + k] = Wh[(i * 16 + (g + 1) * 4 + k) * 64 + lane];
        }
        #pragma unroll
        for (int k = 0; k < 4; ++k) {
            short8 a = ldsA[n * LP + (g * 4 + k) * 4 + q];
            #pragma unroll
            for (int i = 0; i < NT; ++i)
                acc[i] = __builtin_amdgcn_mfma_f32_16x16x32_bf16(
                             a, B[cur][i * 4 + k], acc[i], 0, 0, 0);
        }
    }
}

// ---------------------------------------------------------------------------
// Kernel 2: layer-1 (x REP). 253 blocks x 256. Full body (stage + MFMA +
// store) repeated so per-rep time == true kernel time.
// ---------------------------------------------------------------------------
__global__ __launch_bounds__(256) void layer1_k(
    const float* __restrict__ embed, const float* __restrict__ b1,
    const int* __restrict__ t, float* __restrict__ ws, int z)
{
    __shared__ short8 ldsA[16 * LP];              // 16.6 KB
    const int blk = blockIdx.x, tid = threadIdx.x;
    const bool isPQ = blk < 125;
    const int rowbase = isPQ ? blk * 16 : (blk - 125) * 16;
    const int lane = tid & 63, wv = tid >> 6;
    const int n = lane & 15, q = lane >> 4;

    #pragma unroll 1
    for (int rep = 0; rep < REP; ++rep) {
        const size_t zo = (size_t)(z * rep);
        const short8* W1f = (const short8*)(ws + W1F_OFF + zo);
        __syncthreads();   // previous rep's readers done before restage
        #pragma unroll
        for (int i = 0; i < 4; ++i) {
            int u = i * 256 + tid;
            int r = u >> 6, c = u & 63;
            size_t grow = isPQ ? (size_t)(rowbase + r)
                               : (size_t)t[rowbase + r + zo];
            ldsA[r * LP + c] = cvt8(embed + grow * DIM + c * 8 + zo);
        }
        __syncthreads();

        if (isPQ) {
            const int T0 = wv * 4;
            const int half = (T0 >= 8) ? 1 : 0;    // 0 -> P, 1 -> Q
            const int ntbase = T0 & 7;
            floatx4 acc[4];
            #pragma unroll
            for (int i = 0; i < 4; ++i) acc[i] = (floatx4){0.f, 0.f, 0.f, 0.f};
            const short8* Wh = W1f + (size_t)((half * 8 + ntbase) * 16) * 64;
            l1_core<4>(Wh, ldsA, n, q, lane, acc);
            float* tbl = ws + (half ? NDRUG * H1 : 0) + zo;
            #pragma unroll
            for (int i = 0; i < 4; ++i) {
                int nt = ntbase + i;
                float badd = half ? b1[nt * 16 + n + zo] : 0.f;
                #pragma unroll
                for (int reg = 0; reg < 4; ++reg)
                    tbl[(size_t)(rowbase + q * 4 + reg) * H1 + nt * 16 + n] =
                        acc[i][reg] + badd;
            }
        } else {
            const int ntbase = wv * 2;             // Qt, half 1
            floatx4 acc[2];
            #pragma unroll
            for (int i = 0; i < 2; ++i) acc[i] = (floatx4){0.f, 0.f, 0.f, 0.f};
            const short8* Wh = W1f + (size_t)((8 + ntbase) * 16) * 64;
            l1_core<2>(Wh, ldsA, n, q, lane, acc);
            float* tbl = ws + 2 * (NDRUG * H1) + zo;
            #pragma unroll
            for (int i = 0; i < 2; ++i) {
                int nt = ntbase + i;
                float badd = b1[nt * 16 + n + zo];
                #pragma unroll
                for (int reg = 0; reg < 4; ++reg)
                    tbl[(size_t)(rowbase + q * 4 + reg) * H1 + nt * 16 + n] =
                        acc[i][reg] + badd;
            }
        }
    }
}

// ---------------------------------------------------------------------------
// Kernel 3: score (x REP). 2080 blocks x 256, 1 tile/wave. Full body
// (idx loads + W2f LDS stage + row gather + MFMA + epilogue) repeated.
// ---------------------------------------------------------------------------
__global__ __launch_bounds__(256) void score_k(
    const float* __restrict__ ws,
    const float* __restrict__ b2, const float* __restrict__ W3,
    const float* __restrict__ b3,
    const int* __restrict__ h, const int* __restrict__ ns,
    float* __restrict__ out, int z)
{
    __shared__ short8 w2lds[1024];                // 16 KB
    const int tid = threadIdx.x;
    const int lane = tid & 63, wv = tid >> 6;
    const int tile = blockIdx.x * 4 + wv;          // 0..8319
    const int n = lane & 15, q = lane >> 4;

    const int sg   = tile * 16 + n;
    const int b    = sg / NITEM;
    const int item = sg - b * NITEM;
    const bool midQ = (item >= 1 && item <= 32);

    #pragma unroll 1
    for (int rep = 0; rep < REP; ++rep) {
        const size_t zo = (size_t)(z * rep);
        const float* P  = ws + zo;
        const float* Q  = ws + NDRUG * H1 + zo;
        const float* Qt = ws + 2 * (NDRUG * H1) + zo;
        const short8* W2f = (const short8*)(ws + W2F_OFF + zo);

        const int rowA = (item <= 32) ? h[b + zo]
                                      : ns[b * 64 + 32 + (item - 33) + zo];
        const int rowB = midQ ? ns[b * 64 + item - 1 + zo] : b;

        __syncthreads();   // previous rep's w2lds readers done
        #pragma unroll
        for (int i = 0; i < 4; ++i)
            w2lds[i * 256 + tid] = W2f[i * 256 + tid];
        __syncthreads();

        const float* Pr = P + (size_t)rowA * H1;
        const float* Qr = (midQ ? Q : Qt) + (size_t)rowB * H1;

        float4 pr[8], qr[8];
        #pragma unroll
        for (int kt = 0; kt < 4; ++kt) {
            const int kb = kt * 32 + q * 8;
            pr[kt * 2]     = *(const float4*)(Pr + kb);
            pr[kt * 2 + 1] = *(const float4*)(Pr + kb + 4);
            qr[kt * 2]     = *(const float4*)(Qr + kb);
            qr[kt * 2 + 1] = *(const float4*)(Qr + kb + 4);
        }

        floatx4 acc[4];
        #pragma unroll
        for (int nt = 0; nt < 4; ++nt) acc[nt] = (floatx4){0.f, 0.f, 0.f, 0.f};

        #pragma unroll
        for (int kt = 0; kt < 4; ++kt) {
            float4 p0 = pr[kt * 2], p1 = pr[kt * 2 + 1];
            float4 q0 = qr[kt * 2], q1 = qr[kt * 2 + 1];
            union { short8 s; unsigned u[4]; } A;
            A.u[0] = pkbf(fmaxf(p0.x + q0.x, 0.f), fmaxf(p0.y + q0.y, 0.f));
            A.u[1] = pkbf(fmaxf(p0.z + q0.z, 0.f), fmaxf(p0.w + q0.w, 0.f));
            A.u[2] = pkbf(fmaxf(p1.x + q1.x, 0.f), fmaxf(p1.y + q1.y, 0.f));
            A.u[3] = pkbf(fmaxf(p1.z + q1.z, 0.f), fmaxf(p1.w + q1.w, 0.f));
            #pragma unroll
            for (int nt = 0; nt < 4; ++nt) {
                short8 bf = w2lds[(kt * 4 + nt) * 64 + lane];
                acc[nt] = __builtin_amdgcn_mfma_f32_16x16x32_bf16(A.s, bf, acc[nt], 0, 0, 0);
            }
        }

        float part[4];
        #pragma unroll
        for (int reg = 0; reg < 4; ++reg) {
            float sum = 0.f;
            #pragma unroll
            for (int nt = 0; nt < 4; ++nt) {
                int j = nt * 16 + n;
                sum = fmaf(fmaxf(acc[nt][reg] + b2[j + zo], 0.f), W3[j + zo], sum);
            }
            part[reg] = sum;
        }
        #pragma unroll
        for (int m = 1; m < 16; m <<= 1) {
            #pragma unroll
            for (int reg = 0; reg < 4; ++reg)
                part[reg] += __shfl_xor(part[reg], m, 64);
        }
        if (n == 0) {
            const float base3 = b3[zo];
            #pragma unroll
            for (int reg = 0; reg < 4; ++reg) {
                int gid = tile * 16 + q * 4 + reg;
                int bb  = gid / NITEM;
                int it  = gid - bb * NITEM;
                float val = part[reg] + base3;
                if (it == 0) out[bb + zo] = val;
                else         out[BATCH + bb * 64 + (it - 1) + zo] = val;
            }
        }
    }
}

extern "C" void kernel_launch(void* const* d_in, const int* in_sizes, int n_in,
                              void* d_out, int out_size, void* d_ws, size_t ws_size,
                              hipStream_t stream) {
    const float* embed = (const float*)d_in[0];
    const float* W1    = (const float*)d_in[1];
    const float* b1    = (const float*)d_in[2];
    const float* W2    = (const float*)d_in[3];
    const float* b2    = (const float*)d_in[4];
    const float* W3    = (const float*)d_in[5];
    const float* b3    = (const float*)d_in[6];
    const int*   h     = (const int*)d_in[7];
    const int*   t     = (const int*)d_in[8];
    const int*   ns    = (const int*)d_in[9];
    float* out = (float*)d_out;
    float* ws  = (float*)d_ws;   // slab | W2f | W1f  (~3.4 MB)
    const int z = 0;             // runtime zero: defeats rep-loop hoisting

    pack_w<<<65, 256, 0, stream>>>(W1, W2, ws, z);
    layer1_k<<<253, 256, 0, stream>>>(embed, b1, t, ws, z);
    score_k<<<(BATCH * NITEM) / 64, 256, 0, stream>>>(ws, b2, W3, b3,
                                                      h, ns, out, z);
}

// Round 12
// 116.411 us; speedup vs baseline: 2.0145x; 2.0145x over previous
//
#include <hip/hip_runtime.h>

#define DIM    512
#define BATCH  2048
#define NDRUG  2000
#define H1     128
#define H2     64
#define NITEM  65        // 1 pos + 64 neg per sample
#define SLAB   774144    // floats: P 2000x128 | Q 2000x128 | Qt 2048x128
#define W2F_OFF  (SLAB)               // 16 KB  W2 bf16 B-fragments
#define W1F_OFF  (W2F_OFF + 4096)     // 256 KB W1 bf16 B-fragments
#define LP       65                   // layer1 LDS pitch in short8 (+1 pad)

typedef __attribute__((ext_vector_type(8))) short short8;
typedef __attribute__((ext_vector_type(4))) float floatx4;

// f32 -> bf16 RNE (bit trick; inputs finite)
__device__ inline unsigned f2bf(float x) {
    union { float f; unsigned u; } v; v.f = x;
    unsigned r = v.u + 0x7fffu + ((v.u >> 16) & 1u);
    return r >> 16;
}
__device__ inline unsigned pkbf(float a, float b) {
    return f2bf(a) | (f2bf(b) << 16);
}
__device__ inline short8 cvt8(const float* __restrict__ src) {
    float4 a = *(const float4*)src, b = *(const float4*)(src + 4);
    union { short8 s; unsigned u[4]; } v;
    v.u[0] = pkbf(a.x, a.y); v.u[1] = pkbf(a.z, a.w);
    v.u[2] = pkbf(b.x, b.y); v.u[3] = pkbf(b.z, b.w);
    return v.s;
}

// ---------------------------------------------------------------------------
// Kernel 1: weight packing (single-shot, R10-proven). 65 blocks x 256.
// B-frag: lane L holds B[k=kt*32+(L>>4)*8+j][n=nt*16+(L&15)], j=0..7.
// W1f index = (half*8 + nt)*16 + kt ; W2f index = kt*4 + nt.
// ---------------------------------------------------------------------------
__global__ __launch_bounds__(256) void pack_w(
    const float* __restrict__ W1, const float* __restrict__ W2,
    float* __restrict__ ws)
{
    const int blk = blockIdx.x, tid = threadIdx.x;
    if (blk < 64) {
        short8* W1f = (short8*)(ws + W1F_OFF);
        int item = blk * 256 + tid;                // < 16384
        int frag = item >> 6, fl = item & 63;
        int half = frag >> 7, rem = frag & 127;
        int nt = rem >> 4, kt = rem & 15;
        int fn = fl & 15, fq = fl >> 4;
        short8 v;
        #pragma unroll
        for (int j = 0; j < 8; ++j) {
            int k = half * DIM + kt * 32 + fq * 8 + j;
            v[j] = (short)f2bf(W1[k * H1 + nt * 16 + fn]);
        }
        W1f[item] = v;
    } else {
        short8* W2f = (short8*)(ws + W2F_OFF);
        #pragma unroll
        for (int i = 0; i < 4; ++i) {
            int item = i * 256 + tid;              // < 1024
            int frag = item >> 6, fl = item & 63;
            int kt = frag >> 2, nt = frag & 3;
            int fn = fl & 15, fq = fl >> 4;
            short8 v;
            #pragma unroll
            for (int j = 0; j < 8; ++j)
                v[j] = (short)f2bf(W2[(kt * 32 + fq * 8 + j) * H2 + nt * 16 + fn]);
            W2f[item] = v;
        }
    }
}

// ---------------------------------------------------------------------------
// layer-1 MFMA core (R10-proven): NT col-tiles, K=512, double-buffered bulk
// B-loads. Frag (i,kt) at Wh[(i*16 + kt)*64 + lane].
// ---------------------------------------------------------------------------
template<int NT>
__device__ inline void l1_core(const short8* __restrict__ Wh,
                               const short8* __restrict__ ldsA,
                               int n, int q, int lane, floatx4* acc)
{
    short8 B[2][NT * 4];
    #pragma unroll
    for (int i = 0; i < NT; ++i)
        #pragma unroll
        for (int k = 0; k < 4; ++k)
            B[0][i * 4 + k] = Wh[(i * 16 + k) * 64 + lane];

    #pragma unroll
    for (int g = 0; g < 4; ++g) {
        const int cur = g & 1, nxt = cur ^ 1;
        if (g < 3) {
            #pragma unroll
            for (int i = 0; i < NT; ++i)
                #pragma unroll
                for (int k = 0; k < 4; ++k)
                    B[nxt][i * 4 + k] = Wh[(i * 16 + (g + 1) * 4 + k) * 64 + lane];
        }
        #pragma unroll
        for (int k = 0; k < 4; ++k) {
            short8 a = ldsA[n * LP + (g * 4 + k) * 4 + q];
            #pragma unroll
            for (int i = 0; i < NT; ++i)
                acc[i] = __builtin_amdgcn_mfma_f32_16x16x32_bf16(
                             a, B[cur][i * 4 + k], acc[i], 0, 0, 0);
        }
    }
}

// ---------------------------------------------------------------------------
// Kernel 2: layer-1 (single-shot, R10-proven). 253 blocks x 256.
// ---------------------------------------------------------------------------
__global__ __launch_bounds__(256) void layer1_k(
    const float* __restrict__ embed, const float* __restrict__ b1,
    const int* __restrict__ t, float* __restrict__ ws)
{
    __shared__ short8 ldsA[16 * LP];              // 16.6 KB
    const short8* W1f = (const short8*)(ws + W1F_OFF);
    const int blk = blockIdx.x, tid = threadIdx.x;
    const bool isPQ = blk < 125;
    const int rowbase = isPQ ? blk * 16 : (blk - 125) * 16;
    const int lane = tid & 63, wv = tid >> 6;
    const int n = lane & 15, q = lane >> 4;

    #pragma unroll
    for (int i = 0; i < 4; ++i) {
        int u = i * 256 + tid;
        int r = u >> 6, c = u & 63;
        size_t grow = isPQ ? (size_t)(rowbase + r) : (size_t)t[rowbase + r];
        ldsA[r * LP + c] = cvt8(embed + grow * DIM + c * 8);
    }
    __syncthreads();

    if (isPQ) {
        const int T0 = wv * 4;
        const int half = (T0 >= 8) ? 1 : 0;        // 0 -> P, 1 -> Q
        const int ntbase = T0 & 7;
        floatx4 acc[4];
        #pragma unroll
        for (int i = 0; i < 4; ++i) acc[i] = (floatx4){0.f, 0.f, 0.f, 0.f};
        const short8* Wh = W1f + (size_t)((half * 8 + ntbase) * 16) * 64;
        l1_core<4>(Wh, ldsA, n, q, lane, acc);
        float* tbl = ws + (half ? NDRUG * H1 : 0);
        #pragma unroll
        for (int i = 0; i < 4; ++i) {
            int nt = ntbase + i;
            float badd = half ? b1[nt * 16 + n] : 0.f;
            #pragma unroll
            for (int reg = 0; reg < 4; ++reg)
                tbl[(size_t)(rowbase + q * 4 + reg) * H1 + nt * 16 + n] =
                    acc[i][reg] + badd;
        }
    } else {
        const int ntbase = wv * 2;                 // Qt, half 1
        floatx4 acc[2];
        #pragma unroll
        for (int i = 0; i < 2; ++i) acc[i] = (floatx4){0.f, 0.f, 0.f, 0.f};
        const short8* Wh = W1f + (size_t)((8 + ntbase) * 16) * 64;
        l1_core<2>(Wh, ldsA, n, q, lane, acc);
        float* tbl = ws + 2 * (NDRUG * H1);
        #pragma unroll
        for (int i = 0; i < 2; ++i) {
            int nt = ntbase + i;
            float badd = b1[nt * 16 + n];
            #pragma unroll
            for (int reg = 0; reg < 4; ++reg)
                tbl[(size_t)(rowbase + q * 4 + reg) * H1 + nt * 16 + n] =
                    acc[i][reg] + badd;
        }
    }
}

// ---------------------------------------------------------------------------
// Kernel 3: score v3 — pipelined. 520 blocks x 256; each wave owns 4
// consecutive tiles. All 4 tiles' sample indices loaded up front (one
// exposed round); P/Q rows double-buffered so tile i+1's gather overlaps
// tile i's MFMA+epilogue. W2f staged once per block. launch_bounds(256,2)
// -> 256-VGPR budget for the 128-reg row double buffer; 2080 waves fill
// 2 waves/SIMD residency.
// ---------------------------------------------------------------------------
__global__ __launch_bounds__(256, 2) void score_k(
    const float* __restrict__ ws,
    const float* __restrict__ b2, const float* __restrict__ W3,
    const float* __restrict__ b3,
    const int* __restrict__ h, const int* __restrict__ ns,
    float* __restrict__ out)
{
    __shared__ short8 w2lds[1024];                // 16 KB
    const float* P  = ws;
    const float* Q  = ws + NDRUG * H1;
    const float* Qt = Q + NDRUG * H1;
    const short8* W2f = (const short8*)(ws + W2F_OFF);

    const int tid = threadIdx.x;
    const int lane = tid & 63, wv = tid >> 6;
    const int tbase = blockIdx.x * 16 + wv * 4;    // this wave's first tile
    const int n = lane & 15, q = lane >> 4;

    // All 4 tiles' indices up front — single exposed idx-latency round.
    int rowA[4], rowB[4]; bool midQ[4];
    #pragma unroll
    for (int i = 0; i < 4; ++i) {
        int sg   = (tbase + i) * 16 + n;
        int b    = sg / NITEM;
        int item = sg - b * NITEM;
        midQ[i] = (item >= 1 && item <= 32);
        rowA[i] = (item <= 32) ? h[b] : ns[b * 64 + 32 + (item - 33)];
        rowB[i] = midQ[i] ? ns[b * 64 + item - 1] : b;
    }

    // Stage W2f into LDS (once per block).
    #pragma unroll
    for (int i = 0; i < 4; ++i)
        w2lds[i * 256 + tid] = W2f[i * 256 + tid];
    __syncthreads();

    float4 pr[2][8], qr[2][8];
    // Prime the pipeline: tile 0 rows into buffer 0.
    {
        const float* Pr = P + (size_t)rowA[0] * H1;
        const float* Qr = (midQ[0] ? Q : Qt) + (size_t)rowB[0] * H1;
        #pragma unroll
        for (int kt = 0; kt < 4; ++kt) {
            const int kb = kt * 32 + q * 8;
            pr[0][kt * 2]     = *(const float4*)(Pr + kb);
            pr[0][kt * 2 + 1] = *(const float4*)(Pr + kb + 4);
            qr[0][kt * 2]     = *(const float4*)(Qr + kb);
            qr[0][kt * 2 + 1] = *(const float4*)(Qr + kb + 4);
        }
    }

    const float base3 = b3[0];
    #pragma unroll
    for (int i = 0; i < 4; ++i) {
        const int cur = i & 1, nxt = cur ^ 1;
        if (i < 3) {   // prefetch next tile's rows — overlaps compute below
            const float* Pr = P + (size_t)rowA[i + 1] * H1;
            const float* Qr = (midQ[i + 1] ? Q : Qt) + (size_t)rowB[i + 1] * H1;
            #pragma unroll
            for (int kt = 0; kt < 4; ++kt) {
                const int kb = kt * 32 + q * 8;
                pr[nxt][kt * 2]     = *(const float4*)(Pr + kb);
                pr[nxt][kt * 2 + 1] = *(const float4*)(Pr + kb + 4);
                qr[nxt][kt * 2]     = *(const float4*)(Qr + kb);
                qr[nxt][kt * 2 + 1] = *(const float4*)(Qr + kb + 4);
            }
        }

        floatx4 acc[4];
        #pragma unroll
        for (int nt = 0; nt < 4; ++nt) acc[nt] = (floatx4){0.f, 0.f, 0.f, 0.f};

        #pragma unroll
        for (int kt = 0; kt < 4; ++kt) {
            float4 p0 = pr[cur][kt * 2], p1 = pr[cur][kt * 2 + 1];
            float4 q0 = qr[cur][kt * 2], q1 = qr[cur][kt * 2 + 1];
            union { short8 s; unsigned u[4]; } A;
            A.u[0] = pkbf(fmaxf(p0.x + q0.x, 0.f), fmaxf(p0.y + q0.y, 0.f));
            A.u[1] = pkbf(fmaxf(p0.z + q0.z, 0.f), fmaxf(p0.w + q0.w, 0.f));
            A.u[2] = pkbf(fmaxf(p1.x + q1.x, 0.f), fmaxf(p1.y + q1.y, 0.f));
            A.u[3] = pkbf(fmaxf(p1.z + q1.z, 0.f), fmaxf(p1.w + q1.w, 0.f));
            #pragma unroll
            for (int nt = 0; nt < 4; ++nt) {
                short8 bf = w2lds[(kt * 4 + nt) * 64 + lane];
                acc[nt] = __builtin_amdgcn_mfma_f32_16x16x32_bf16(A.s, bf, acc[nt], 0, 0, 0);
            }
        }

        float part[4];
        #pragma unroll
        for (int reg = 0; reg < 4; ++reg) {
            float sum = 0.f;
            #pragma unroll
            for (int nt = 0; nt < 4; ++nt) {
                int j = nt * 16 + n;
                sum = fmaf(fmaxf(acc[nt][reg] + b2[j], 0.f), W3[j], sum);
            }
            part[reg] = sum;
        }
        #pragma unroll
        for (int m = 1; m < 16; m <<= 1) {
            #pragma unroll
            for (int reg = 0; reg < 4; ++reg)
                part[reg] += __shfl_xor(part[reg], m, 64);
        }
        if (n == 0) {
            #pragma unroll
            for (int reg = 0; reg < 4; ++reg) {
                int gid = (tbase + i) * 16 + q * 4 + reg;
                int bb  = gid / NITEM;
                int it  = gid - bb * NITEM;
                float val = part[reg] + base3;
                if (it == 0) out[bb] = val;
                else         out[BATCH + bb * 64 + (it - 1)] = val;
            }
        }
    }
}

extern "C" void kernel_launch(void* const* d_in, const int* in_sizes, int n_in,
                              void* d_out, int out_size, void* d_ws, size_t ws_size,
                              hipStream_t stream) {
    const float* embed = (const float*)d_in[0];
    const float* W1    = (const float*)d_in[1];
    const float* b1    = (const float*)d_in[2];
    const float* W2    = (const float*)d_in[3];
    const float* b2    = (const float*)d_in[4];
    const float* W3    = (const float*)d_in[5];
    const float* b3    = (const float*)d_in[6];
    const int*   h     = (const int*)d_in[7];
    const int*   t     = (const int*)d_in[8];
    const int*   ns    = (const int*)d_in[9];
    float* out = (float*)d_out;
    float* ws  = (float*)d_ws;   // slab | W2f | W1f  (~3.4 MB)

    pack_w<<<65, 256, 0, stream>>>(W1, W2, ws);
    layer1_k<<<253, 256, 0, stream>>>(embed, b1, t, ws);
    score_k<<<520, 256, 0, stream>>>(ws, b2, W3, b3, h, ns, out);
}

// Round 13
// 115.151 us; speedup vs baseline: 2.0366x; 1.0109x over previous
//
#include <hip/hip_runtime.h>

#define DIM    512
#define BATCH  2048
#define NDRUG  2000
#define H1     128
#define H2     64
#define NITEM  65        // 1 pos + 64 neg per sample
#define SLAB   774144    // floats: P 2000x128 | Q 2000x128 | Qt 2048x128
#define W2F_OFF  (SLAB)               // 16 KB  W2 bf16 B-fragments
#define W1F_OFF  (W2F_OFF + 4096)     // 256 KB W1 bf16 B-fragments
#define LP       65                   // layer1 LDS pitch in short8 (+1 pad)

typedef __attribute__((ext_vector_type(8))) short short8;
typedef __attribute__((ext_vector_type(4))) float floatx4;

// f32 -> bf16 RNE (bit trick; inputs finite)
__device__ inline unsigned f2bf(float x) {
    union { float f; unsigned u; } v; v.f = x;
    unsigned r = v.u + 0x7fffu + ((v.u >> 16) & 1u);
    return r >> 16;
}
__device__ inline unsigned pkbf(float a, float b) {
    return f2bf(a) | (f2bf(b) << 16);
}
__device__ inline short8 cvt8(const float* __restrict__ src) {
    float4 a = *(const float4*)src, b = *(const float4*)(src + 4);
    union { short8 s; unsigned u[4]; } v;
    v.u[0] = pkbf(a.x, a.y); v.u[1] = pkbf(a.z, a.w);
    v.u[2] = pkbf(b.x, b.y); v.u[3] = pkbf(b.z, b.w);
    return v.s;
}

// ---------------------------------------------------------------------------
// Kernel 1: weight packing. 65 blocks x 256.
// B-frag (mfma_f32_16x16x32_bf16): lane L holds
//   B[k = kt*32 + (L>>4)*8 + j][n = nt*16 + (L&15)], j=0..7.
// W1f storage index = (half*8 + nt)*16 + kt ; W2f storage index = kt*4 + nt.
// ---------------------------------------------------------------------------
__global__ __launch_bounds__(256) void pack_w(
    const float* __restrict__ W1, const float* __restrict__ W2,
    float* __restrict__ ws)
{
    const int blk = blockIdx.x, tid = threadIdx.x;
    if (blk < 64) {
        short8* W1f = (short8*)(ws + W1F_OFF);
        int item = blk * 256 + tid;                // < 16384
        int frag = item >> 6, fl = item & 63;
        int half = frag >> 7, rem = frag & 127;
        int nt = rem >> 4, kt = rem & 15;
        int fn = fl & 15, fq = fl >> 4;
        short8 v;
        #pragma unroll
        for (int j = 0; j < 8; ++j) {
            int k = half * DIM + kt * 32 + fq * 8 + j;
            v[j] = (short)f2bf(W1[k * H1 + nt * 16 + fn]);
        }
        W1f[item] = v;
    } else {
        short8* W2f = (short8*)(ws + W2F_OFF);
        #pragma unroll
        for (int i = 0; i < 4; ++i) {
            int item = i * 256 + tid;              // < 1024
            int frag = item >> 6, fl = item & 63;
            int kt = frag >> 2, nt = frag & 3;
            int fn = fl & 15, fq = fl >> 4;
            short8 v;
            #pragma unroll
            for (int j = 0; j < 8; ++j)
                v[j] = (short)f2bf(W2[(kt * 32 + fq * 8 + j) * H2 + nt * 16 + fn]);
            W2f[item] = v;
        }
    }
}

// ---------------------------------------------------------------------------
// layer-1 MFMA core: NT column-tiles, K=512, double-buffered bulk B-loads
// (4-kt groups) so exposed global latency is ~4 rounds, overlapped with MFMA.
// Frag (i,kt) at Wh[(i*16 + kt)*64 + lane].
// ---------------------------------------------------------------------------
template<int NT>
__device__ inline void l1_core(const short8* __restrict__ Wh,
                               const short8* __restrict__ ldsA,
                               int n, int q, int lane, floatx4* acc)
{
    short8 B[2][NT * 4];
    #pragma unroll
    for (int i = 0; i < NT; ++i)
        #pragma unroll
        for (int k = 0; k < 4; ++k)
            B[0][i * 4 + k] = Wh[(i * 16 + k) * 64 + lane];

    #pragma unroll
    for (int g = 0; g < 4; ++g) {
        const int cur = g & 1, nxt = cur ^ 1;
        if (g < 3) {
            #pragma unroll
            for (int i = 0; i < NT; ++i)
                #pragma unroll
                for (int k = 0; k < 4; ++k)
                    B[nxt][i * 4 + k] = Wh[(i * 16 + (g + 1) * 4 + k) * 64 + lane];
        }
        #pragma unroll
        for (int k = 0; k < 4; ++k) {
            short8 a = ldsA[n * LP + (g * 4 + k) * 4 + q];
            #pragma unroll
            for (int i = 0; i < NT; ++i)
                acc[i] = __builtin_amdgcn_mfma_f32_16x16x32_bf16(
                             a, B[cur][i * 4 + k], acc[i], 0, 0, 0);
        }
    }
}

// ---------------------------------------------------------------------------
// Kernel 2: layer-1. 253 blocks x 256. embed staged f32->bf16 into LDS in
// A-frag order. blk<125: 16 drug rows, waves cover P nt0-7 / Q nt0-7
// (4 tiles each). blk>=125: 16 t-gathered rows, waves cover Qt nt0-7
// (2 tiles each). b1 folded into tail tables (Q, Qt).
// ---------------------------------------------------------------------------
__global__ __launch_bounds__(256) void layer1_k(
    const float* __restrict__ embed, const float* __restrict__ b1,
    const int* __restrict__ t, float* __restrict__ ws)
{
    __shared__ short8 ldsA[16 * LP];              // 16.6 KB
    const short8* W1f = (const short8*)(ws + W1F_OFF);
    const int blk = blockIdx.x, tid = threadIdx.x;
    const bool isPQ = blk < 125;
    const int rowbase = isPQ ? blk * 16 : (blk - 125) * 16;
    const int lane = tid & 63, wv = tid >> 6;
    const int n = lane & 15, q = lane >> 4;

    #pragma unroll
    for (int i = 0; i < 4; ++i) {
        int u = i * 256 + tid;
        int r = u >> 6, c = u & 63;
        size_t grow = isPQ ? (size_t)(rowbase + r) : (size_t)t[rowbase + r];
        ldsA[r * LP + c] = cvt8(embed + grow * DIM + c * 8);
    }
    __syncthreads();

    if (isPQ) {
        const int T0 = wv * 4;
        const int half = (T0 >= 8) ? 1 : 0;        // 0 -> P, 1 -> Q
        const int ntbase = T0 & 7;
        floatx4 acc[4];
        #pragma unroll
        for (int i = 0; i < 4; ++i) acc[i] = (floatx4){0.f, 0.f, 0.f, 0.f};
        const short8* Wh = W1f + (size_t)((half * 8 + ntbase) * 16) * 64;
        l1_core<4>(Wh, ldsA, n, q, lane, acc);
        float* tbl = ws + (half ? NDRUG * H1 : 0);
        #pragma unroll
        for (int i = 0; i < 4; ++i) {
            int nt = ntbase + i;
            float badd = half ? b1[nt * 16 + n] : 0.f;
            #pragma unroll
            for (int reg = 0; reg < 4; ++reg)
                tbl[(size_t)(rowbase + q * 4 + reg) * H1 + nt * 16 + n] =
                    acc[i][reg] + badd;
        }
    } else {
        const int ntbase = wv * 2;                 // Qt, half 1
        floatx4 acc[2];
        #pragma unroll
        for (int i = 0; i < 2; ++i) acc[i] = (floatx4){0.f, 0.f, 0.f, 0.f};
        const short8* Wh = W1f + (size_t)((8 + ntbase) * 16) * 64;
        l1_core<2>(Wh, ldsA, n, q, lane, acc);
        float* tbl = ws + 2 * (NDRUG * H1);
        #pragma unroll
        for (int i = 0; i < 2; ++i) {
            int nt = ntbase + i;
            float badd = b1[nt * 16 + n];
            #pragma unroll
            for (int reg = 0; reg < 4; ++reg)
                tbl[(size_t)(rowbase + q * 4 + reg) * H1 + nt * 16 + n] =
                    acc[i][reg] + badd;
        }
    }
}

// ---------------------------------------------------------------------------
// Kernel 3: score (R10-proven best). 2080 blocks x 256, 1 tile/wave,
// 8 blocks/CU TLP. W2f staged into LDS per block; sample indices loaded
// BEFORE the staging barrier (latency overlap); all 16 P/Q row float4s
// bulk-loaded in one round; MFMA B-operands from LDS. Epilogue relu+W3 +
// 16-lane shuffle reduce.
// ---------------------------------------------------------------------------
__global__ __launch_bounds__(256) void score_k(
    const float* __restrict__ ws,
    const float* __restrict__ b2, const float* __restrict__ W3,
    const float* __restrict__ b3,
    const int* __restrict__ h, const int* __restrict__ ns,
    float* __restrict__ out)
{
    __shared__ short8 w2lds[1024];                // 16 KB
    const float* P  = ws;
    const float* Q  = ws + NDRUG * H1;
    const float* Qt = Q + NDRUG * H1;
    const short8* W2f = (const short8*)(ws + W2F_OFF);

    const int tid = threadIdx.x;
    const int lane = tid & 63, wv = tid >> 6;
    const int tile = blockIdx.x * 4 + wv;          // 0..8319
    const int n = lane & 15, q = lane >> 4;

    // Index loads issued before the staging barrier — latency overlaps.
    const int sg   = tile * 16 + n;
    const int b    = sg / NITEM;
    const int item = sg - b * NITEM;
    const bool midQ = (item >= 1 && item <= 32);
    const int rowA = (item <= 32) ? h[b] : ns[b * 64 + 32 + (item - 33)];
    const int rowB = midQ ? ns[b * 64 + item - 1] : b;

    // Stage W2f into LDS (coalesced, 4 short8 per thread).
    #pragma unroll
    for (int i = 0; i < 4; ++i)
        w2lds[i * 256 + tid] = W2f[i * 256 + tid];
    __syncthreads();

    const float* Pr = P + (size_t)rowA * H1;
    const float* Qr = (midQ ? Q : Qt) + (size_t)rowB * H1;

    // Bulk-load all 16 row float4s -> one exposed latency round.
    float4 pr[8], qr[8];
    #pragma unroll
    for (int kt = 0; kt < 4; ++kt) {
        const int kb = kt * 32 + q * 8;
        pr[kt * 2]     = *(const float4*)(Pr + kb);
        pr[kt * 2 + 1] = *(const float4*)(Pr + kb + 4);
        qr[kt * 2]     = *(const float4*)(Qr + kb);
        qr[kt * 2 + 1] = *(const float4*)(Qr + kb + 4);
    }

    floatx4 acc[4];
    #pragma unroll
    for (int nt = 0; nt < 4; ++nt) acc[nt] = (floatx4){0.f, 0.f, 0.f, 0.f};

    #pragma unroll
    for (int kt = 0; kt < 4; ++kt) {
        float4 p0 = pr[kt * 2], p1 = pr[kt * 2 + 1];
        float4 q0 = qr[kt * 2], q1 = qr[kt * 2 + 1];
        union { short8 s; unsigned u[4]; } A;
        A.u[0] = pkbf(fmaxf(p0.x + q0.x, 0.f), fmaxf(p0.y + q0.y, 0.f));
        A.u[1] = pkbf(fmaxf(p0.z + q0.z, 0.f), fmaxf(p0.w + q0.w, 0.f));
        A.u[2] = pkbf(fmaxf(p1.x + q1.x, 0.f), fmaxf(p1.y + q1.y, 0.f));
        A.u[3] = pkbf(fmaxf(p1.z + q1.z, 0.f), fmaxf(p1.w + q1.w, 0.f));
        #pragma unroll
        for (int nt = 0; nt < 4; ++nt) {
            short8 bf = w2lds[(kt * 4 + nt) * 64 + lane];
            acc[nt] = __builtin_amdgcn_mfma_f32_16x16x32_bf16(A.s, bf, acc[nt], 0, 0, 0);
        }
    }

    float part[4];
    #pragma unroll
    for (int reg = 0; reg < 4; ++reg) {
        float sum = 0.f;
        #pragma unroll
        for (int nt = 0; nt < 4; ++nt) {
            int j = nt * 16 + n;
            sum = fmaf(fmaxf(acc[nt][reg] + b2[j], 0.f), W3[j], sum);
        }
        part[reg] = sum;
    }
    #pragma unroll
    for (int m = 1; m < 16; m <<= 1) {
        #pragma unroll
        for (int reg = 0; reg < 4; ++reg)
            part[reg] += __shfl_xor(part[reg], m, 64);
    }
    if (n == 0) {
        const float base3 = b3[0];
        #pragma unroll
        for (int reg = 0; reg < 4; ++reg) {
            int gid = tile * 16 + q * 4 + reg;
            int bb  = gid / NITEM;
            int it  = gid - bb * NITEM;
            float val = part[reg] + base3;
            if (it == 0) out[bb] = val;
            else         out[BATCH + bb * 64 + (it - 1)] = val;
        }
    }
}

extern "C" void kernel_launch(void* const* d_in, const int* in_sizes, int n_in,
                              void* d_out, int out_size, void* d_ws, size_t ws_size,
                              hipStream_t stream) {
    const float* embed = (const float*)d_in[0];
    const float* W1    = (const float*)d_in[1];
    const float* b1    = (const float*)d_in[2];
    const float* W2    = (const float*)d_in[3];
    const float* b2    = (const float*)d_in[4];
    const float* W3    = (const float*)d_in[5];
    const float* b3    = (const float*)d_in[6];
    const int*   h     = (const int*)d_in[7];
    const int*   t     = (const int*)d_in[8];
    const int*   ns    = (const int*)d_in[9];
    float* out = (float*)d_out;
    float* ws  = (float*)d_ws;   // slab | W2f | W1f  (~3.4 MB)

    pack_w<<<65, 256, 0, stream>>>(W1, W2, ws);
    layer1_k<<<253, 256, 0, stream>>>(embed, b1, t, ws);
    score_k<<<(BATCH * NITEM) / 64, 256, 0, stream>>>(ws, b2, W3, b3,
                                                      h, ns, out);
}